// Round 12
// baseline (92.744 us; speedup 1.0000x reference)
//
#include <hip/hip_runtime.h>

typedef _Float16 f16x8 __attribute__((ext_vector_type(8)));
typedef float f32x16 __attribute__((ext_vector_type(16)));

#define NT 16384
#define DM 4096
#define NE 64
#define TOPK 8
#define BTOK 32
#define BK 64
#define NCHK (DM / BK)         // 64
#define XPL 4096               // bytes per x plane in LDS (8 kg * 32 cells * 16B)
#define RSCALE 4.8828125e-4f   // 2^-11
#define NEGINF (-3.402823466e38f)

#define MF(a, b, c) __builtin_amdgcn_mfma_f32_32x32x16_f16((a), (b), (c), 0, 0, 0)

// K-loop barrier: LDS-visibility only. NO vmcnt drain -- global loads stay in
// flight across the barrier (T4). Loop has no global stores, so this is safe;
// the compiler inserts its own counted vmcnt before each use of loaded regs.
#define KBAR() { \
  asm volatile("s_waitcnt lgkmcnt(0)" ::: "memory"); \
  __builtin_amdgcn_s_barrier(); \
  asm volatile("" ::: "memory"); }

// v = h + l*2^-11 + rho, |rho| <= 2^-22 |v|
#define SP(V, H, L, j) { const float _v = (V); const _Float16 _h = (_Float16)_v; \
  H[j] = _h; L[j] = (_Float16)((_v - (float)_h) * 2048.0f); }
#define SPLIT8(F0, F1, H, L) { \
  SP(F0.x, H, L, 0) SP(F0.y, H, L, 1) SP(F0.z, H, L, 2) SP(F0.w, H, L, 3) \
  SP(F1.x, H, L, 4) SP(F1.y, H, L, 5) SP(F1.z, H, L, 6) SP(F1.w, H, L, 7) }

// ---------- pre-kernel: split W into 2 fp16 planes, LINEAR chunk layout ----------
__global__ __launch_bounds__(256) void wsplit_kernel(const float* __restrict__ W,
                                                     _Float16* __restrict__ wsp) {
  const int id = blockIdx.x * 256 + (int)threadIdx.x;   // 0..32767
  const int e = id >> 9, kgg = id & 511;
  const float* src = W + (size_t)e * DM + kgg * 8;
  const float4 a = ((const float4*)src)[0];
  const float4 b = ((const float4*)src)[1];
  f16x8 H, L; SPLIT8(a, b, H, L)
  const int c = kgg >> 3, kg = kgg & 7;
  *(f16x8*)(wsp + ((size_t)(c * 2) * 512 + kg * 64 + e) * 8) = H;
  *(f16x8*)(wsp + ((size_t)(c * 2 + 1) * 512 + kg * 64 + e) * 8) = L;
}

// ---------- main kernel ----------
template<bool PRE>
__global__ __launch_bounds__(256, 2) void gate_kernel(
    const float* __restrict__ x, const float* __restrict__ W,
    const _Float16* __restrict__ wsp, int* __restrict__ out) {

  __shared__ __align__(16) char xsmem[2][2 * XPL];   // x only: 16 KB
  __shared__ float lg[BTOK][68];

  const int t = (int)threadIdx.x;
  const int lane = t & 63;
  const int w = t >> 6;                 // 4 waves
  const int et = w & 1, kh = w >> 1;    // expert half, K half
  const int l31 = lane & 31, lhi = lane >> 5;
  const int kh4 = kh * 4;
  const int ecol = et * 32 + l31;
  const int tok0 = blockIdx.x * BTOK;

  // x staging: thread -> (tok = t>>3, kg = t&7), 8 floats (256B runs, coalesced)
  const int sxtok = t >> 3, sxkg = t & 7;
  const float* xg = x + (size_t)(tok0 + sxtok) * DM + sxkg * 8;
  const int xoff0 = (sxkg * 32 + ((sxtok + sxkg) & 31)) * 16;   // rotated cells

  // B direct-load base (PRE): lane -> cell (kg, ecol); per half-wave 512B runs
  const _Float16* wb = PRE ? (wsp + ((size_t)(kh4 + lhi) * 64 + ecol) * 8) : nullptr;
  const float* wf = W + (size_t)ecol * DM + (kh4 + lhi) * 8;   // fallback

  f32x16 acc0 = {}, acc1 = {}, acc2 = {};

  float4 XA0, XA1, XB0, XB1;
  f16x8 B0h0, B0l0, B0h1, B0l1, B1h0, B1l0, B1h1, B1l1;

#define LOADX(c, Xp) { const float* _s = xg + (c) * BK; \
  Xp##0 = *(const float4*)_s; Xp##1 = *(const float4*)(_s + 4); }

#define LOADB(c, Bp) { \
  if (PRE) { \
    const _Float16* _q = wb + (size_t)(c) * 8192; \
    Bp##h0 = *(const f16x8*)(_q); \
    Bp##h1 = *(const f16x8*)(_q + 1024); \
    Bp##l0 = *(const f16x8*)(_q + 4096); \
    Bp##l1 = *(const f16x8*)(_q + 5120); \
  } else { \
    const float* _p = wf + (size_t)(c) * BK; \
    const float4 _a0 = ((const float4*)_p)[0], _a1 = ((const float4*)_p)[1]; \
    const float4 _b0 = ((const float4*)(_p + 16))[0], _b1 = ((const float4*)(_p + 16))[1]; \
    SPLIT8(_a0, _a1, Bp##h0, Bp##l0) \
    SPLIT8(_b0, _b1, Bp##h1, Bp##l1) \
  } }

#define WRX(bn, Xp) { \
  f16x8 XH, XL; SPLIT8(Xp##0, Xp##1, XH, XL) \
  char* _b = xsmem[bn]; \
  *(f16x8*)(_b + xoff0) = XH; \
  *(f16x8*)(_b + XPL + xoff0) = XL; }

  // A and B use IDENTICAL (lhi,slot)->k mapping (R9-R11 validated).
#define KSTEP(bn, Bp, ks) { \
  const int _kg = kh4 + (ks) * 2 + lhi; \
  const int _ao = (_kg * 32 + ((l31 + _kg) & 31)) * 16; \
  const char* _b = xsmem[bn]; \
  const f16x8 ah = *(const f16x8*)(_b + _ao); \
  const f16x8 al = *(const f16x8*)(_b + XPL + _ao); \
  acc0 = MF(ah, Bp##h##ks, acc0); \
  acc1 = MF(ah, Bp##l##ks, acc1); \
  acc2 = MF(al, Bp##h##ks, acc2); }

#define BODY(c, Xw, Xl, Bc, Bn) { \
  if ((c) + 2 < NCHK) LOADX((c) + 2, Xl) \
  if ((c) + 1 < NCHK) LOADB((c) + 1, Bn) \
  KSTEP((c) & 1, Bc, 0) \
  KSTEP((c) & 1, Bc, 1) \
  if ((c) + 1 < NCHK) WRX(((c) + 1) & 1, Xw) \
  KBAR() }

  // ---- prologue ----
  LOADX(0, XA)
  WRX(0, XA)
  LOADB(0, B0)
  LOADX(1, XA)
  __syncthreads();

  // ---- main loop: 2 chunks per iteration (static reg ping-pong) ----
  for (int c = 0; c < NCHK; c += 2) {
    BODY(c,     XA, XB, B0, B1)
    BODY(c + 1, XB, XA, B1, B0)
  }

  // ---- merge K halves (reuse xsmem[0]: 8 KB), build logits ----
  float* mg = (float*)xsmem[0];
  if (kh == 1) {
#pragma unroll 16
    for (int i = 0; i < 16; ++i)
      mg[et * 1024 + i * 64 + lane] = acc0[i] + (acc1[i] + acc2[i]) * RSCALE;
  }
  __syncthreads();
  if (kh == 0) {
#pragma unroll 16
    for (int i = 0; i < 16; ++i) {
      const float v = acc0[i] + (acc1[i] + acc2[i]) * RSCALE
                    + mg[et * 1024 + i * 64 + lane];
      const int row = (i & 3) + ((i >> 2) << 3) + (lhi << 2);  // verified C/D map
      lg[row][ecol] = v;
    }
  }
  __syncthreads();

  // ---- top-8 per token: lane = expert, ballot-argmax (R8-R11 validated) ----
#define PICK(p) { \
  float m = v; \
  m = fmaxf(m, __shfl_xor(m, 32)); \
  m = fmaxf(m, __shfl_xor(m, 16)); \
  m = fmaxf(m, __shfl_xor(m, 8));  \
  m = fmaxf(m, __shfl_xor(m, 4));  \
  m = fmaxf(m, __shfl_xor(m, 2));  \
  m = fmaxf(m, __shfl_xor(m, 1));  \
  const unsigned long long bm = __ballot(v == m); \
  const int ii = (int)__builtin_ctzll(bm); \
  idx##p = ii; \
  v = (lane == ii) ? NEGINF : v; }

  for (int tt = 0; tt < 8; ++tt) {
    const int trow = w * 8 + tt;
    float v = lg[trow][lane];
    int idx0, idx1, idx2, idx3, idx4, idx5, idx6, idx7;
    PICK(0) PICK(1) PICK(2) PICK(3) PICK(4) PICK(5) PICK(6) PICK(7)
    if (lane == 0) {
      int4* op = (int4*)(out + (size_t)(tok0 + trow) * TOPK);
      op[0] = make_int4(idx0, idx1, idx2, idx3);
      op[1] = make_int4(idx4, idx5, idx6, idx7);
    }
  }
}

extern "C" void kernel_launch(void* const* d_in, const int* in_sizes, int n_in,
                              void* d_out, int out_size, void* d_ws, size_t ws_size,
                              hipStream_t stream) {
  const float* x = (const float*)d_in[0];
  const float* W = (const float*)d_in[1];
  int* out = (int*)d_out;
  (void)in_sizes; (void)n_in; (void)out_size;

  const size_t need = (size_t)NE * DM * 2 * sizeof(_Float16);  // 1 MB
  if (ws_size >= need && d_ws != nullptr) {
    _Float16* wsp = (_Float16*)d_ws;
    hipLaunchKernelGGL(wsplit_kernel, dim3(128), dim3(256), 0, stream, W, wsp);
    hipLaunchKernelGGL((gate_kernel<true>), dim3(NT / BTOK), dim3(256),
                       0, stream, x, W, (const _Float16*)wsp, out);
  } else {
    hipLaunchKernelGGL((gate_kernel<false>), dim3(NT / BTOK), dim3(256),
                       0, stream, x, W, (const _Float16*)nullptr, out);
  }
}

// Round 13
// 76.060 us; speedup vs baseline: 1.2193x; 1.2193x over previous
//
#include <hip/hip_runtime.h>

typedef _Float16 f16x8 __attribute__((ext_vector_type(8)));
typedef float f32x16 __attribute__((ext_vector_type(16)));

#define NT 16384
#define DM 4096
#define NE 64
#define TOPK 8
#define BTOK 32
#define BK 128
#define NCHK (DM / BK)         // 32
#define XPL 8192               // bytes per x plane in LDS (16 kg * 32 cells * 16B)
#define RSCALE 4.8828125e-4f   // 2^-11
#define NEGINF (-3.402823466e38f)

#define MF(a, b, c) __builtin_amdgcn_mfma_f32_32x32x16_f16((a), (b), (c), 0, 0, 0)

// v = h + l*2^-11 + rho, |rho| <= 2^-22 |v|
#define SP(V, H, L, j) { const float _v = (V); const _Float16 _h = (_Float16)_v; \
  H[j] = _h; L[j] = (_Float16)((_v - (float)_h) * 2048.0f); }
#define SPLIT8(F0, F1, H, L) { \
  SP(F0.x, H, L, 0) SP(F0.y, H, L, 1) SP(F0.z, H, L, 2) SP(F0.w, H, L, 3) \
  SP(F1.x, H, L, 4) SP(F1.y, H, L, 5) SP(F1.z, H, L, 6) SP(F1.w, H, L, 7) }

// ---------- pre-kernel: split W into 2 fp16 planes, BK=128 chunk layout ----------
// wsp elem ((c*2+p)*1024 + kg*64 + e)*8 + j  <->  W[e][c*128 + kg*8 + j], plane p
__global__ __launch_bounds__(256) void wsplit_kernel(const float* __restrict__ W,
                                                     _Float16* __restrict__ wsp) {
  const int id = blockIdx.x * 256 + (int)threadIdx.x;   // 0..32767
  const int e = id >> 9, kgg = id & 511;
  const float* src = W + (size_t)e * DM + kgg * 8;
  const float4 a = ((const float4*)src)[0];
  const float4 b = ((const float4*)src)[1];
  f16x8 H, L; SPLIT8(a, b, H, L)
  const int c = kgg >> 4, kg = kgg & 15;
  _Float16* dst = wsp + ((size_t)(c * 2) * 1024 + kg * 64 + e) * 8;
  *(f16x8*)dst = H;
  *(f16x8*)(dst + 8192) = L;     // +1 plane (1024 cells * 8)
}

// ---------- main kernel: 8 waves = 2 expert-halves x 4 K-quarters ----------
template<bool PRE>
__global__ __launch_bounds__(512, 4) void gate_kernel(
    const float* __restrict__ x, const float* __restrict__ W,
    const _Float16* __restrict__ wsp, int* __restrict__ out) {

  __shared__ __align__(16) char xsmem[2][2 * XPL];   // x only: 32 KB
  __shared__ float lg[BTOK][68];

  const int t = (int)threadIdx.x;
  const int lane = t & 63;
  const int w = t >> 6;                 // 8 waves
  const int et = w & 1, kq = w >> 1;    // expert half, K quarter
  const int l31 = lane & 31, lhi = lane >> 5;
  const int ecol = et * 32 + l31;
  const int tok0 = blockIdx.x * BTOK;

  // x staging: thread -> (tok = t>>4, kg = t&15), 8 floats (512B runs, coalesced)
  const int sxtok = t >> 4, sxkg = t & 15;
  const float* xg = x + (size_t)(tok0 + sxtok) * DM + sxkg * 8;
  const int xoff0 = (sxkg * 32 + ((sxtok + sxkg) & 31)) * 16;   // rotated cells

  // B direct-load base (PRE): lane -> cell (kg = kq*4 + ks*2 + lhi, ecol)
  const _Float16* wb = PRE ? (wsp + ((size_t)(kq * 4 + lhi) * 64 + ecol) * 8) : nullptr;
  const float* wf = W + (size_t)ecol * DM + (kq * 4 + lhi) * 8;   // fallback

  f32x16 acc0 = {}, acc1 = {};

  float4 XA0, XA1, XB0, XB1;
  f16x8 B0h0, B0l0, B0h1, B0l1, B1h0, B1l0, B1h1, B1l1;

#define LOADX(c, Xp) { const float* _s = xg + (c) * BK; \
  Xp##0 = *(const float4*)_s; Xp##1 = *(const float4*)(_s + 4); }

#define LOADB(c, Bp) { \
  if (PRE) { \
    const _Float16* _q = wb + (size_t)(c) * 16384; \
    Bp##h0 = *(const f16x8*)(_q); \
    Bp##h1 = *(const f16x8*)(_q + 1024);   /* ks=1: +2 kg = 128 cells */ \
    Bp##l0 = *(const f16x8*)(_q + 8192);   /* low plane */ \
    Bp##l1 = *(const f16x8*)(_q + 9216); \
  } else { \
    const float* _p = wf + (size_t)(c) * BK; \
    const float4 _a0 = ((const float4*)_p)[0], _a1 = ((const float4*)_p)[1]; \
    const float4 _b0 = ((const float4*)(_p + 16))[0], _b1 = ((const float4*)(_p + 16))[1]; \
    SPLIT8(_a0, _a1, Bp##h0, Bp##l0) \
    SPLIT8(_b0, _b1, Bp##h1, Bp##l1) \
  } }

#define WRX(bn, Xp) { \
  f16x8 XH, XL; SPLIT8(Xp##0, Xp##1, XH, XL) \
  char* _b = xsmem[bn]; \
  *(f16x8*)(_b + xoff0) = XH; \
  *(f16x8*)(_b + XPL + xoff0) = XL; }

  // A and B use IDENTICAL (kg, within-cell j) -> k mapping (R9-R12 validated:
  // k-map errors cancel; C/D map verified).
#define KSTEP(bn, Bp, ks) { \
  const int _kg = kq * 4 + (ks) * 2 + lhi; \
  const int _ao = (_kg * 32 + ((l31 + _kg) & 31)) * 16; \
  const char* _b = xsmem[bn]; \
  const f16x8 ah = *(const f16x8*)(_b + _ao); \
  const f16x8 al = *(const f16x8*)(_b + XPL + _ao); \
  acc0 = MF(ah, Bp##h##ks, acc0); \
  acc1 = MF(ah, Bp##l##ks, acc1); \
  acc1 = MF(al, Bp##h##ks, acc1); }

#define BODY(c, Xw, Xl, Bc, Bn) { \
  if ((c) + 2 < NCHK) LOADX((c) + 2, Xl) \
  if ((c) + 1 < NCHK) LOADB((c) + 1, Bn) \
  KSTEP((c) & 1, Bc, 0) \
  KSTEP((c) & 1, Bc, 1) \
  if ((c) + 1 < NCHK) WRX(((c) + 1) & 1, Xw) \
  __syncthreads(); }

  // ---- prologue ----
  LOADX(0, XA)
  WRX(0, XA)
  LOADB(0, B0)
  LOADX(1, XA)
  __syncthreads();

  // ---- main loop: 2 chunks per iteration (static reg ping-pong) ----
  for (int c = 0; c < NCHK; c += 2) {
    BODY(c,     XA, XB, B0, B1)
    BODY(c + 1, XB, XA, B1, B0)
  }

  // ---- combine planes in-register ----
#pragma unroll 16
  for (int i = 0; i < 16; ++i) acc0[i] += acc1[i] * RSCALE;

  // ---- merge 4 K-quarters via LDS tree (reuse xsmem: 4 slots x 4 KB) ----
  float* mg = (float*)xsmem;
  // round 1: kq 1 -> slot(et,0), kq 3 -> slot(et,1)
  if (kq == 1 || kq == 3) {
    float* s = mg + (et * 2 + (kq >> 1)) * 1024;
#pragma unroll 16
    for (int i = 0; i < 16; ++i) s[i * 64 + lane] = acc0[i];
  }
  __syncthreads();
  if (kq == 0 || kq == 2) {
    const float* s = mg + (et * 2 + (kq >> 1)) * 1024;
#pragma unroll 16
    for (int i = 0; i < 16; ++i) acc0[i] += s[i * 64 + lane];
  }
  __syncthreads();
  // round 2: kq 2 -> slot(et,0)
  if (kq == 2) {
    float* s = mg + (et * 2) * 1024;
#pragma unroll 16
    for (int i = 0; i < 16; ++i) s[i * 64 + lane] = acc0[i];
  }
  __syncthreads();
  if (kq == 0) {
    const float* s = mg + (et * 2) * 1024;
#pragma unroll 16
    for (int i = 0; i < 16; ++i) {
      const float v = acc0[i] + s[i * 64 + lane];
      const int row = (i & 3) + ((i >> 2) << 3) + (lhi << 2);  // verified C/D map
      lg[row][ecol] = v;
    }
  }
  __syncthreads();

  // ---- top-8 per token: lane = expert, ballot-argmax (R8-R12 validated) ----
#define PICK(p) { \
  float m = v; \
  m = fmaxf(m, __shfl_xor(m, 32)); \
  m = fmaxf(m, __shfl_xor(m, 16)); \
  m = fmaxf(m, __shfl_xor(m, 8));  \
  m = fmaxf(m, __shfl_xor(m, 4));  \
  m = fmaxf(m, __shfl_xor(m, 2));  \
  m = fmaxf(m, __shfl_xor(m, 1));  \
  const unsigned long long bm = __ballot(v == m); \
  const int ii = (int)__builtin_ctzll(bm); \
  idx##p = ii; \
  v = (lane == ii) ? NEGINF : v; }

  {
    const int trow0 = w * 4;
#pragma unroll
    for (int tt = 0; tt < 4; ++tt) {
      const int trow = trow0 + tt;
      float v = lg[trow][lane];
      int idx0, idx1, idx2, idx3, idx4, idx5, idx6, idx7;
      PICK(0) PICK(1) PICK(2) PICK(3) PICK(4) PICK(5) PICK(6) PICK(7)
      if (lane == 0) {
        int4* op = (int4*)(out + (size_t)(tok0 + trow) * TOPK);
        op[0] = make_int4(idx0, idx1, idx2, idx3);
        op[1] = make_int4(idx4, idx5, idx6, idx7);
      }
    }
  }
}

extern "C" void kernel_launch(void* const* d_in, const int* in_sizes, int n_in,
                              void* d_out, int out_size, void* d_ws, size_t ws_size,
                              hipStream_t stream) {
  const float* x = (const float*)d_in[0];
  const float* W = (const float*)d_in[1];
  int* out = (int*)d_out;
  (void)in_sizes; (void)n_in; (void)out_size;

  const size_t need = (size_t)NE * DM * 2 * sizeof(_Float16);  // 1 MB
  if (ws_size >= need && d_ws != nullptr) {
    _Float16* wsp = (_Float16*)d_ws;
    hipLaunchKernelGGL(wsplit_kernel, dim3(128), dim3(256), 0, stream, W, wsp);
    hipLaunchKernelGGL((gate_kernel<true>), dim3(NT / BTOK), dim3(512),
                       0, stream, x, W, (const _Float16*)wsp, out);
  } else {
    hipLaunchKernelGGL((gate_kernel<false>), dim3(NT / BTOK), dim3(512),
                       0, stream, x, W, (const _Float16*)nullptr, out);
  }
}